// Round 3
// baseline (82.302 us; speedup 1.0000x reference)
//
#include <hip/hip_runtime.h>
#include <hip/hip_bf16.h>

// EmbeddingMul2: out[b,s,:] = embedding[input_[b,s], :]
// input_:    (8, 256) int32   -> 2048 indices in [0, 50000)
// embedding: (50000, 256) fp32
// out:       (8, 256, 256) fp32 = 524288 floats = 2 MiB
//
// Pure gather, 4 MiB total traffic -> launch/harness-overhead-bound.
// One wave (64 lanes) copies one 256-float row via 16B vector ops
// (16 B/lane * 64 lanes = 1024 B = one full row).
//  - readfirstlane on wave id -> idx load compiles to scalar s_load (broadcast)
//  - nontemporal 16B store (native ext_vector_type, not HIP float4 class)

#define NUM_DIMS 256
#define NUM_ROWS 2048  // 8 * 256 indices

typedef float v4f __attribute__((ext_vector_type(4)));

__global__ __launch_bounds__(256) void EmbeddingMul2_16183436772039_kernel(
    const int* __restrict__ idx,
    const float* __restrict__ emb,
    float* __restrict__ out) {
    int wave = __builtin_amdgcn_readfirstlane(threadIdx.x >> 6);
    int lane = threadIdx.x & 63;           // 16B slot within the row
    int row  = blockIdx.x * 4 + wave;      // one row per wave

    int e = idx[row];                      // wave-uniform -> SGPR load

    const v4f* __restrict__ src = (const v4f*)(emb + (size_t)e * NUM_DIMS);
    v4f* __restrict__ dst       = (v4f*)(out + (size_t)row * NUM_DIMS);
    v4f v = src[lane];
    __builtin_nontemporal_store(v, &dst[lane]);
}

extern "C" void kernel_launch(void* const* d_in, const int* in_sizes, int n_in,
                              void* d_out, int out_size, void* d_ws, size_t ws_size,
                              hipStream_t stream) {
    const int*   idx = (const int*)d_in[0];    // input_  (8*256 int32)
    const float* emb = (const float*)d_in[1];  // embedding (50000*256 fp32)
    float*       out = (float*)d_out;          // (8,256,256) fp32

    dim3 grid(NUM_ROWS / 4);  // 4 rows (waves) per 256-thread block
    dim3 block(256);
    EmbeddingMul2_16183436772039_kernel<<<grid, block, 0, stream>>>(idx, emb, out);
}